// Round 6
// baseline (235.044 us; speedup 1.0000x reference)
//
#include <hip/hip_runtime.h>
#include <hip/hip_bf16.h>

#define EPS 1e-3f
#define NPIX  50176   // 16*56*56
#define NOPIX 12544   // 16*28*28

// ws float offsets
#define OFF_S2   0        // [32][4]  s2
#define OFF_T2   128      // [32][4]  t2
#define OFF_T3   256      // [128]
#define OFF_BSUM 384      // [256]
#define OFF_W3S  640      // [128 k][36 = 9kk x 4ci] pre-scaled by s3
#define OFF_T3P  5248     // [32 g][128 c]  t' = bn1 shift in relu(x+t') form
#define OFF_WAF  9344     // A-frag table: [32 g][4 kk][64 lane][8 bf16] (32768 floats)
#define OFF_U    42112    // [32 g][50176 px] ushort4 (bf16, g-planar)
#define OFF_V    3253376  // [12544 opx][128 k] f32 conv3 output (post BN3+ReLU)

typedef __attribute__((ext_vector_type(8))) short short8v;
typedef __attribute__((ext_vector_type(4))) float f32x4;

__device__ __forceinline__ unsigned short f2bf(float f) {
    unsigned u = __float_as_uint(f);
    return (unsigned short)((u + 0x7fffu + ((u >> 16) & 1u)) >> 16);
}
__device__ __forceinline__ float bf2f(unsigned short s) {
    return __uint_as_float(((unsigned)s) << 16);
}
__device__ __forceinline__ unsigned pk2bf(float lo, float hi) {
    __hip_bfloat162 p = __float22bfloat162_rn(make_float2(lo, hi)); // RNE, lo in bits[15:0]
    union { __hip_bfloat162 h; unsigned u; } c; c.h = p;
    return c.u;
}

__global__ __launch_bounds__(256)
void prep_kernel(const float* __restrict__ g1, const float* __restrict__ be1,
                 const float* __restrict__ m1, const float* __restrict__ v1,
                 const float* __restrict__ W1, const float* __restrict__ b1,
                 const float* __restrict__ g2, const float* __restrict__ be2,
                 const float* __restrict__ m2, const float* __restrict__ v2,
                 const float* __restrict__ W3, const float* __restrict__ b3,
                 const float* __restrict__ g3, const float* __restrict__ be3,
                 const float* __restrict__ m3, const float* __restrict__ v3,
                 const float* __restrict__ b2, float* __restrict__ ws) {
    int gid = blockIdx.x * 256 + threadIdx.x;
    int stride = gridDim.x * 256;
    // t' table [g][c]: relu(bn1(x)) = s1 * relu(x + t'), t' = be1/s1 - m1
    for (int i = gid; i < 4096; i += stride) {
        float s = g1[i] * rsqrtf(v1[i] + EPS);
        ws[OFF_T3P + i] = be1[i] / s - m1[i];
    }
    // W' A-fragment table (bf16): lane l holds A[m=l&15][k=(l>>4)*8+j], m=f (<4), k=c within kk-slice
    {
        unsigned short* wsu = (unsigned short*)(ws + OFF_WAF);
        for (int i = gid; i < 65536; i += stride) {
            int j    = i & 7;
            int lane = (i >> 3) & 63;
            int kk   = (i >> 9) & 3;
            int g    = i >> 11;
            int f    = lane & 15;
            int c    = kk*32 + (lane >> 4)*8 + j;
            unsigned short v = 0;
            if (f < 4) {
                float s = g1[g*128 + c] * rsqrtf(v1[g*128 + c] + EPS);
                v = f2bf(s * W1[g*512 + c*4 + f]);
            }
            wsu[i] = v;
        }
    }
    // W3 re-laid [k][kk*4+ci], pre-scaled by s3  (k = g*4+f)
    for (int i = gid; i < 4608; i += stride) {
        int k = i / 36, j = i - k*36;
        int kk = j >> 2, ci = j & 3;
        int g = k >> 2, f = k & 3;
        float s3 = g3[k] * rsqrtf(v3[k] + EPS);
        ws[OFF_W3S + i] = W3[g*144 + kk*16 + ci*4 + f] * s3;
    }
    if (gid < 128) {
        float s2 = g2[gid] * rsqrtf(v2[gid] + EPS);
        ws[OFF_S2 + gid] = s2;
        ws[OFF_T2 + gid] = be2[gid] + (b1[gid] - m2[gid]) * s2;
        float s3 = g3[gid] * rsqrtf(v3[gid] + EPS);
        ws[OFF_T3 + gid] = be3[gid] + (b3[gid] - m3[gid]) * s3;
    } else if (gid >= 256 && gid < 512) {
        int co = gid - 256;
        float acc = 0.f;
        for (int g = 0; g < 32; ++g) acc += b2[g*256 + co];
        ws[OFF_BSUM + co] = acc;
    }
}

// Stage 1 (MFMA, zero-LDS, zero-barrier): grid = 8 g-octs x 784 tiles
// (blockIdx = goct*784 + tile so tile-sharing blocks land on one XCD).
// Block 256 = 4 waves; wave = 1 group x 64 px, fully independent.
// A-frags (16 VGPR) + t' (32 VGPR) + epilogue consts in registers; x read
// straight from global in B-frag layout (8 dwordx4 per t = one 8KB px-slab).
__global__ __launch_bounds__(256)
void stage1_kernel(const float* __restrict__ x,
                   const float* __restrict__ tabs,   // ws
                   float* __restrict__ uout) {       // ws + OFF_U
    int tid  = threadIdx.x;
    int tile = blockIdx.x % 784;
    int goct = blockIdx.x / 784;                    // 0..7
    int lane = tid & 63;
    int wid  = tid >> 6;                            // 0..3
    int g    = __builtin_amdgcn_readfirstlane(goct*4 + wid);
    int l15  = lane & 15;
    int lq   = lane >> 4;                           // k-chunk: c = kk*32 + lq*8 + j

    // A-fragments (t-invariant): 4 kk x 16B = 16 VGPR
    union U4S { uint4 u; short8v s; };
    U4S af[4];
    {
        const uint4* wafp = (const uint4*)(tabs + OFF_WAF);
        #pragma unroll
        for (int kk = 0; kk < 4; ++kk)
            af[kk].u = wafp[(g*4 + kk)*64 + lane];
    }
    // t' in registers: 8 f32x4 (this lane's lq-slice), 32 VGPR
    f32x4 tpr[8];
    {
        const f32x4* tpg = (const f32x4*)(tabs + OFF_T3P) + g*32 + lq*2;
        #pragma unroll
        for (int kk = 0; kk < 4; ++kk) {
            tpr[kk*2]   = tpg[kk*8];
            tpr[kk*2+1] = tpg[kk*8 + 1];
        }
    }
    const float4 s2v = ((const float4*)(tabs + OFF_S2))[g];
    const float4 t2v = ((const float4*)(tabs + OFF_T2))[g];

    uint2* Uo = (uint2*)uout;
    const f32x4 zro = {0.f, 0.f, 0.f, 0.f};

    #pragma unroll 1
    for (int t = 0; t < 4; ++t) {
        // x in B-frag layout, straight from global (contiguous 8KB slab per wave)
        const f32x4* xp = (const f32x4*)x + (size_t)(tile*64 + t*16 + l15)*32 + lq*2;
        f32x4 xf[8];
        #pragma unroll
        for (int kk = 0; kk < 4; ++kk) {
            xf[kk*2]   = xp[kk*8];
            xf[kk*2+1] = xp[kk*8 + 1];
        }
        f32x4 acc = zro;
        #pragma unroll
        for (int kk = 0; kk < 4; ++kk) {
            f32x4 za = __builtin_elementwise_max(xf[kk*2]   + tpr[kk*2],   zro);
            f32x4 zb = __builtin_elementwise_max(xf[kk*2+1] + tpr[kk*2+1], zro);
            union { unsigned u[4]; short8v s; } zz;
            zz.u[0] = pk2bf(za[0], za[1]);
            zz.u[1] = pk2bf(za[2], za[3]);
            zz.u[2] = pk2bf(zb[0], zb[1]);
            zz.u[3] = pk2bf(zb[2], zb[3]);
            acc = __builtin_amdgcn_mfma_f32_16x16x32_bf16(af[kk].s, zz.s, acc, 0, 0, 0);
        }
        // epilogue: lane<16 holds px = t*16+l15's f0..3 in acc[0..3]
        float o0 = fmaxf(fmaf(acc[0], s2v.x, t2v.x), 0.f);
        float o1 = fmaxf(fmaf(acc[1], s2v.y, t2v.y), 0.f);
        float o2 = fmaxf(fmaf(acc[2], s2v.z, t2v.z), 0.f);
        float o3 = fmaxf(fmaf(acc[3], s2v.w, t2v.w), 0.f);
        uint2 val;
        val.x = pk2bf(o0, o1);
        val.y = pk2bf(o2, o3);
        if (lane < 16)
            Uo[(size_t)g * NPIX + tile*64 + t*16 + lane] = val;
    }
}

// Stage 2a: 3x3 stride-2 conv. Block = quarter-row (7 opx), 256 thr, grid 1792.
__global__ __launch_bounds__(256)
void stage2a_kernel(const float* __restrict__ tabs,   // ws
                    const float* __restrict__ U,      // ws + OFF_U (bf16)
                    float* __restrict__ V) {          // ws + OFF_V
    __shared__ ushort4 patch[3*16*32];   // [r][c][g ^ c]   12288 B

    int tid = threadIdx.x;
    int row = blockIdx.x >> 2;           // b*28 + oh
    int q   = blockIdx.x & 3;            // quarter: opx = q*7 .. q*7+6
    int b = row / 28, oh = row - b*28;

    // ---- stage U patch: rows ih = 2oh-1..2oh+1, cols ic = 14q-1 .. 14q+13 ----
    {
        const ushort4* Uu = (const ushort4*)U;
        #pragma unroll 1
        for (int i = tid; i < 1440; i += 256) {
            int g = i / 45;
            int rem = i - g*45;
            int r = rem / 15;            // 0..2
            int c = rem - r*15;          // 0..14
            int ih = 2*oh - 1 + r;
            int ic = 14*q - 1 + c;
            ushort4 v = make_ushort4(0, 0, 0, 0);
            if (ih >= 0 && ic >= 0)
                v = Uu[(size_t)g * NPIX + (b*56 + ih)*56 + ic];
            patch[(r*16 + c)*32 + (g ^ c)] = v;
        }
    }

    // weights into VGPRs: 9 float4 per thread (L2-hot table)
    int k = tid & 127, s = tid >> 7;     // s in {0,1}
    int g = k >> 2;
    float4 w[9];
    {
        const float4* wk = (const float4*)(tabs + OFF_W3S + k*36);
        #pragma unroll
        for (int kk = 0; kk < 9; ++kk) w[kk] = wk[kk];
    }
    float t3 = tabs[OFF_T3 + k];
    __syncthreads();

    // ---- conv: opx_l = s + 2j (parity split), each ushort4 read broadcast x4 f ----
    #pragma unroll
    for (int j = 0; j < 4; ++j) {
        int opx_l = s + 2*j;
        if (opx_l > 6) break;
        float acc = 0.f;
        #pragma unroll
        for (int kh = 0; kh < 3; ++kh) {
            #pragma unroll
            for (int kw = 0; kw < 3; ++kw) {
                int cc = 2*opx_l + kw;   // 0..14
                ushort4 u = patch[(kh*16 + cc)*32 + (g ^ cc)];
                float4 wv = w[kh*3 + kw];
                acc = fmaf(bf2f(u.x), wv.x, acc);
                acc = fmaf(bf2f(u.y), wv.y, acc);
                acc = fmaf(bf2f(u.z), wv.z, acc);
                acc = fmaf(bf2f(u.w), wv.w, acc);
            }
        }
        int opx = row*28 + q*7 + opx_l;
        V[(size_t)opx*128 + k] = fmaxf(acc + t3, 0.f);
    }
}

// Stage 2b: 1x1 conv (GEMM) + bsum + residual. Block = 8 opx, 256 thr, grid 1568.
__global__ __launch_bounds__(256)
void stage2b_kernel(const float* __restrict__ x,
                    const float* __restrict__ W2,     // [128,256]
                    const float* __restrict__ tabs,   // ws
                    const float* __restrict__ V,      // ws + OFF_V
                    float* __restrict__ out) {
    __shared__ float vs[8*128];
    __shared__ float res_s[8];
    int tid = threadIdx.x;
    int opxBase = blockIdx.x * 8;

    // stage V rows (coalesced)
    {
        const float* Vb = V + (size_t)opxBase * 128;
        #pragma unroll
        for (int jj = 0; jj < 4; ++jj) vs[tid + 256*jj] = Vb[tid + 256*jj];
    }
    // residual: res[p] = sum_c x[b, 2oh, 2ow, c]
    {
        int p = tid >> 5, l = tid & 31;
        int opx = opxBase + p;
        int b = opx / 784, r = opx - b*784;
        int oh = r / 28, ow = r - oh*28;
        const float* xp = x + (size_t)((b*56 + 2*oh)*56 + 2*ow) * 128;
        float rv = xp[l] + xp[l+32] + xp[l+64] + xp[l+96];
        #pragma unroll
        for (int off = 16; off; off >>= 1) rv += __shfl_down(rv, off, 32);
        if (l == 0) res_s[p] = rv;
    }
    __syncthreads();

    // out[opx][co] = vs @ W2 + bsum + res, thread = co
    int co = tid;
    float acc[8];
    {
        float bs = tabs[OFF_BSUM + co];
        #pragma unroll
        for (int p = 0; p < 8; ++p) acc[p] = bs;
    }
    const float* W2c = W2 + co;
    #pragma unroll 4
    for (int k4 = 0; k4 < 32; ++k4) {
        float w0 = W2c[(4*k4+0)*256];
        float w1 = W2c[(4*k4+1)*256];
        float w2 = W2c[(4*k4+2)*256];
        float w3 = W2c[(4*k4+3)*256];
        #pragma unroll
        for (int p = 0; p < 8; ++p) {
            float4 v = *(const float4*)&vs[p*128 + k4*4];   // broadcast
            acc[p] = fmaf(v.x, w0, acc[p]);
            acc[p] = fmaf(v.y, w1, acc[p]);
            acc[p] = fmaf(v.z, w2, acc[p]);
            acc[p] = fmaf(v.w, w3, acc[p]);
        }
    }
    #pragma unroll
    for (int p = 0; p < 8; ++p)
        out[(size_t)(opxBase + p)*256 + co] = acc[p] + res_s[p];
}

extern "C" void kernel_launch(void* const* d_in, const int* in_sizes, int n_in,
                              void* d_out, int out_size, void* d_ws, size_t ws_size,
                              hipStream_t stream) {
    const float* x   = (const float*)d_in[0];
    const float* g1  = (const float*)d_in[1];
    const float* be1 = (const float*)d_in[2];
    const float* m1  = (const float*)d_in[3];
    const float* v1  = (const float*)d_in[4];
    const float* W1  = (const float*)d_in[5];
    const float* b1  = (const float*)d_in[6];
    const float* g2  = (const float*)d_in[7];
    const float* be2 = (const float*)d_in[8];
    const float* m2  = (const float*)d_in[9];
    const float* v2  = (const float*)d_in[10];
    const float* W3  = (const float*)d_in[11];
    const float* b3  = (const float*)d_in[12];
    const float* g3  = (const float*)d_in[13];
    const float* be3 = (const float*)d_in[14];
    const float* m3  = (const float*)d_in[15];
    const float* v3  = (const float*)d_in[16];
    const float* W2  = (const float*)d_in[17];
    const float* b2  = (const float*)d_in[18];
    float* out = (float*)d_out;
    float* ws  = (float*)d_ws;

    prep_kernel<<<64, 256, 0, stream>>>(g1, be1, m1, v1, W1, b1, g2, be2, m2,
                                        v2, W3, b3, g3, be3, m3, v3, b2, ws);
    stage1_kernel<<<784 * 8, 256, 0, stream>>>(x, ws, ws + OFF_U);
    stage2a_kernel<<<448 * 4, 256, 0, stream>>>(ws, ws + OFF_U, ws + OFF_V);
    stage2b_kernel<<<NOPIX / 8, 256, 0, stream>>>(x, W2, ws, ws + OFF_V, out);
}

// Round 8
// 156.028 us; speedup vs baseline: 1.5064x; 1.5064x over previous
//
#include <hip/hip_runtime.h>
#include <hip/hip_bf16.h>

#define EPS 1e-3f
#define NPIX  50176   // 16*56*56
#define NOPIX 12544   // 16*28*28

// ws float offsets
#define OFF_S2   0        // [32][4]  s2
#define OFF_T2   128      // [32][4]  t2
#define OFF_T3   256      // [128]
#define OFF_BSUM 384      // [256]
#define OFF_W3S  640      // [128 k][36 = 9kk x 4ci] pre-scaled by s3
#define OFF_TPH  5248     // [32 g][4 kk][4 lq][8] f16 t' (2048 floats)
#define OFF_WAF  7296     // A-frag table f16: [32 g][4 kk][64 lane][8] (32768 floats)
#define OFF_U    40064    // [32 g][50176 px] ushort4 (bf16, g-planar)
#define OFF_V    3251328  // [12544 opx][128 k] f32 conv3 output (post BN3+ReLU)

typedef __attribute__((ext_vector_type(4))) float f32x4;
typedef __attribute__((ext_vector_type(8))) _Float16 f16x8;
typedef __attribute__((ext_vector_type(4))) _Float16 f16x4;

__device__ __forceinline__ unsigned short f2bf(float f) {
    unsigned u = __float_as_uint(f);
    return (unsigned short)((u + 0x7fffu + ((u >> 16) & 1u)) >> 16);
}
__device__ __forceinline__ float bf2f(unsigned short s) {
    return __uint_as_float(((unsigned)s) << 16);
}
__device__ __forceinline__ unsigned pk2bf(float lo, float hi) {
    __hip_bfloat162 p = __float22bfloat162_rn(make_float2(lo, hi)); // RNE, lo in bits[15:0]
    union { __hip_bfloat162 h; unsigned u; } c; c.h = p;
    return c.u;
}
__device__ __forceinline__ unsigned short f2h(float f) {
    union { _Float16 h; unsigned short u; } c;
    c.h = (_Float16)f;                 // RNE
    return c.u;
}

__global__ __launch_bounds__(256)
void prep_kernel(const float* __restrict__ g1, const float* __restrict__ be1,
                 const float* __restrict__ m1, const float* __restrict__ v1,
                 const float* __restrict__ W1, const float* __restrict__ b1,
                 const float* __restrict__ g2, const float* __restrict__ be2,
                 const float* __restrict__ m2, const float* __restrict__ v2,
                 const float* __restrict__ W3, const float* __restrict__ b3,
                 const float* __restrict__ g3, const float* __restrict__ be3,
                 const float* __restrict__ m3, const float* __restrict__ v3,
                 const float* __restrict__ b2, float* __restrict__ ws) {
    int gid = blockIdx.x * 256 + threadIdx.x;
    int stride = gridDim.x * 256;
    // t' f16 table: [g][kk][lq][j]  c = kk*32 + lq*8 + j ; t' = be1/s1 - m1
    {
        unsigned short* tph = (unsigned short*)(ws + OFF_TPH);
        for (int i = gid; i < 4096; i += stride) {
            int j  = i & 7, lq = (i >> 3) & 3, kk = (i >> 5) & 3, g = i >> 7;
            int c = kk*32 + lq*8 + j;
            float s = g1[g*128 + c] * rsqrtf(v1[g*128 + c] + EPS);
            tph[i] = f2h(be1[g*128 + c] / s - m1[g*128 + c]);
        }
    }
    // W' A-fragment table (f16): lane l holds A[m=l&15][k=(l>>4)*8+j], m=f (<4)
    {
        unsigned short* wsu = (unsigned short*)(ws + OFF_WAF);
        for (int i = gid; i < 65536; i += stride) {
            int j    = i & 7;
            int lane = (i >> 3) & 63;
            int kk   = (i >> 9) & 3;
            int g    = i >> 11;
            int f    = lane & 15;
            int c    = kk*32 + (lane >> 4)*8 + j;
            unsigned short v = 0;
            if (f < 4) {
                float s = g1[g*128 + c] * rsqrtf(v1[g*128 + c] + EPS);
                v = f2h(s * W1[g*512 + c*4 + f]);
            }
            wsu[i] = v;
        }
    }
    // W3 re-laid [k][kk*4+ci], pre-scaled by s3  (k = g*4+f)
    for (int i = gid; i < 4608; i += stride) {
        int k = i / 36, j = i - k*36;
        int kk = j >> 2, ci = j & 3;
        int g = k >> 2, f = k & 3;
        float s3 = g3[k] * rsqrtf(v3[k] + EPS);
        ws[OFF_W3S + i] = W3[g*144 + kk*16 + ci*4 + f] * s3;
    }
    if (gid < 128) {
        float s2 = g2[gid] * rsqrtf(v2[gid] + EPS);
        ws[OFF_S2 + gid] = s2;
        ws[OFF_T2 + gid] = be2[gid] + (b1[gid] - m2[gid]) * s2;
        float s3 = g3[gid] * rsqrtf(v3[gid] + EPS);
        ws[OFF_T3 + gid] = be3[gid] + (b3[gid] - m3[gid]) * s3;
    } else if (gid >= 256 && gid < 512) {
        int co = gid - 256;
        float acc = 0.f;
        for (int g = 0; g < 32; ++g) acc += b2[g*256 + co];
        ws[OFF_BSUM + co] = acc;
    }
}

// Stage 1 (fp16 MFMA): grid = 784 tiles x 2 g-halves; block 512 = 8 waves;
// wave = 2 groups x 64 px. x converted f32->f16 at staging (once); z-compute
// is pure v_pk_add_f16/v_pk_max_f16 (2 elem/inst), no cvt in the g-loop.
// t' + A-frags in registers; x f16 in LDS (16 KB, XOR-swizzled 16B chunks).
__global__ __launch_bounds__(512, 4)
void stage1_kernel(const float* __restrict__ x,
                   const float* __restrict__ tabs,   // ws
                   float* __restrict__ uout) {       // ws + OFF_U
    __shared__ uint4 xs[1024];     // 16 KB: [64 px][16 chunk ^ (px&15)], chunk = 8 f16
    int tid = threadIdx.x;
    int tile  = blockIdx.x >> 1;
    int ghalf = blockIdx.x & 1;

    // stage x -> f16 LDS (coalesced reads; paired ds_write_b64, 2-way free)
    {
        const float4* xg = (const float4*)x + (size_t)tile * 2048;
        #pragma unroll
        for (int r = 0; r < 4; ++r) {
            int i = tid + 512*r;
            int px = i >> 5, c4 = i & 31;
            float4 v = xg[i];
            union { f16x4 h; uint2 u; } hv;
            hv.h = (f16x4){(_Float16)v.x, (_Float16)v.y, (_Float16)v.z, (_Float16)v.w};
            int cc = c4 >> 1, hf = c4 & 1;
            ((uint2*)xs)[(px*16 + (cc ^ (px & 15)))*2 + hf] = hv.u;
        }
    }

    int lane = tid & 63;
    int wid  = tid >> 6;                                   // 0..7
    int g0   = __builtin_amdgcn_readfirstlane(ghalf*16 + wid*2);
    int l15  = lane & 15;
    int lq   = lane >> 4;                                  // k-chunk: c = kk*32 + lq*8 + j

    union U4H { uint4 u; f16x8 h; };
    // A-fragments: 2 g x 4 kk = 32 VGPR (f16)
    U4H af[2][4];
    {
        const uint4* wafp = (const uint4*)(tabs + OFF_WAF);
        #pragma unroll
        for (int gi = 0; gi < 2; ++gi)
            #pragma unroll
            for (int kk = 0; kk < 4; ++kk)
                af[gi][kk].u = wafp[((g0 + gi)*4 + kk)*64 + lane];
    }
    // t' f16 in registers: 2 g x 4 kk x 16B = 32 VGPR
    U4H tph[2][4];
    {
        const uint4* tphp = (const uint4*)(tabs + OFF_TPH);
        #pragma unroll
        for (int gi = 0; gi < 2; ++gi)
            #pragma unroll
            for (int kk = 0; kk < 4; ++kk)
                tph[gi][kk].u = tphp[((g0 + gi)*4 + kk)*4 + lq];
    }
    __syncthreads();

    uint2* Uo = (uint2*)uout;
    const f32x4 zro = {0.f, 0.f, 0.f, 0.f};
    const f16x8 zh = {0, 0, 0, 0, 0, 0, 0, 0};

    #pragma unroll 1
    for (int t = 0; t < 4; ++t) {
        int pxl = t*16 + l15;
        U4H xf[4];
        #pragma unroll
        for (int kk = 0; kk < 4; ++kk)
            xf[kk].u = xs[pxl*16 + ((kk*4 + lq) ^ (pxl & 15))];
        #pragma unroll
        for (int gi = 0; gi < 2; ++gi) {
            int g = g0 + gi;
            f32x4 acc = zro;
            #pragma unroll
            for (int kk = 0; kk < 4; ++kk) {
                f16x8 z = __builtin_elementwise_max(xf[kk].h + tph[gi][kk].h, zh);
                acc = __builtin_amdgcn_mfma_f32_16x16x32_f16(af[gi][kk].h, z, acc, 0, 0, 0);
            }
            // epilogue: lane<16 holds px=pxl's f0..3 in acc[0..3]; g wave-uniform -> s_load
            const float4 s2v = ((const float4*)(tabs + OFF_S2))[g];
            const float4 t2v = ((const float4*)(tabs + OFF_T2))[g];
            float o0 = fmaxf(fmaf(acc[0], s2v.x, t2v.x), 0.f);
            float o1 = fmaxf(fmaf(acc[1], s2v.y, t2v.y), 0.f);
            float o2 = fmaxf(fmaf(acc[2], s2v.z, t2v.z), 0.f);
            float o3 = fmaxf(fmaf(acc[3], s2v.w, t2v.w), 0.f);
            uint2 val;
            val.x = pk2bf(o0, o1);
            val.y = pk2bf(o2, o3);
            if (lane < 16)
                Uo[(size_t)g * NPIX + tile*64 + t*16 + lane] = val;
        }
    }
}

// Stage 2a: 3x3 stride-2 conv. Block = quarter-row (7 opx), 256 thr, grid 1792.
__global__ __launch_bounds__(256)
void stage2a_kernel(const float* __restrict__ tabs,   // ws
                    const float* __restrict__ U,      // ws + OFF_U (bf16)
                    float* __restrict__ V) {          // ws + OFF_V
    __shared__ ushort4 patch[3*16*32];   // [r][c][g ^ c]   12288 B

    int tid = threadIdx.x;
    int row = blockIdx.x >> 2;           // b*28 + oh
    int q   = blockIdx.x & 3;            // quarter: opx = q*7 .. q*7+6
    int b = row / 28, oh = row - b*28;

    // ---- stage U patch: rows ih = 2oh-1..2oh+1, cols ic = 14q-1 .. 14q+13 ----
    {
        const ushort4* Uu = (const ushort4*)U;
        #pragma unroll 1
        for (int i = tid; i < 1440; i += 256) {
            int g = i / 45;
            int rem = i - g*45;
            int r = rem / 15;            // 0..2
            int c = rem - r*15;          // 0..14
            int ih = 2*oh - 1 + r;
            int ic = 14*q - 1 + c;
            ushort4 v = make_ushort4(0, 0, 0, 0);
            if (ih >= 0 && ic >= 0)
                v = Uu[(size_t)g * NPIX + (b*56 + ih)*56 + ic];
            patch[(r*16 + c)*32 + (g ^ c)] = v;
        }
    }

    // weights into VGPRs: 9 float4 per thread (L2-hot table)
    int k = tid & 127, s = tid >> 7;     // s in {0,1}
    int g = k >> 2;
    float4 w[9];
    {
        const float4* wk = (const float4*)(tabs + OFF_W3S + k*36);
        #pragma unroll
        for (int kk = 0; kk < 9; ++kk) w[kk] = wk[kk];
    }
    float t3 = tabs[OFF_T3 + k];
    __syncthreads();

    // ---- conv: opx_l = s + 2j (parity split), each ushort4 read broadcast x4 f ----
    #pragma unroll
    for (int j = 0; j < 4; ++j) {
        int opx_l = s + 2*j;
        if (opx_l > 6) break;
        float acc = 0.f;
        #pragma unroll
        for (int kh = 0; kh < 3; ++kh) {
            #pragma unroll
            for (int kw = 0; kw < 3; ++kw) {
                int cc = 2*opx_l + kw;   // 0..14
                ushort4 u = patch[(kh*16 + cc)*32 + (g ^ cc)];
                float4 wv = w[kh*3 + kw];
                acc = fmaf(bf2f(u.x), wv.x, acc);
                acc = fmaf(bf2f(u.y), wv.y, acc);
                acc = fmaf(bf2f(u.z), wv.z, acc);
                acc = fmaf(bf2f(u.w), wv.w, acc);
            }
        }
        int opx = row*28 + q*7 + opx_l;
        V[(size_t)opx*128 + k] = fmaxf(acc + t3, 0.f);
    }
}

// Stage 2b: 1x1 conv (GEMM) + bsum + residual. Block = 8 opx, 256 thr, grid 1568.
__global__ __launch_bounds__(256)
void stage2b_kernel(const float* __restrict__ x,
                    const float* __restrict__ W2,     // [128,256]
                    const float* __restrict__ tabs,   // ws
                    const float* __restrict__ V,      // ws + OFF_V
                    float* __restrict__ out) {
    __shared__ float vs[8*128];
    __shared__ float res_s[8];
    int tid = threadIdx.x;
    int opxBase = blockIdx.x * 8;

    // stage V rows (coalesced)
    {
        const float* Vb = V + (size_t)opxBase * 128;
        #pragma unroll
        for (int jj = 0; jj < 4; ++jj) vs[tid + 256*jj] = Vb[tid + 256*jj];
    }
    // residual: res[p] = sum_c x[b, 2oh, 2ow, c]
    {
        int p = tid >> 5, l = tid & 31;
        int opx = opxBase + p;
        int b = opx / 784, r = opx - b*784;
        int oh = r / 28, ow = r - oh*28;
        const float* xp = x + (size_t)((b*56 + 2*oh)*56 + 2*ow) * 128;
        float rv = xp[l] + xp[l+32] + xp[l+64] + xp[l+96];
        #pragma unroll
        for (int off = 16; off; off >>= 1) rv += __shfl_down(rv, off, 32);
        if (l == 0) res_s[p] = rv;
    }
    __syncthreads();

    // out[opx][co] = vs @ W2 + bsum + res, thread = co
    int co = tid;
    float acc[8];
    {
        float bs = tabs[OFF_BSUM + co];
        #pragma unroll
        for (int p = 0; p < 8; ++p) acc[p] = bs;
    }
    const float* W2c = W2 + co;
    #pragma unroll 4
    for (int k4 = 0; k4 < 32; ++k4) {
        float w0 = W2c[(4*k4+0)*256];
        float w1 = W2c[(4*k4+1)*256];
        float w2 = W2c[(4*k4+2)*256];
        float w3 = W2c[(4*k4+3)*256];
        #pragma unroll
        for (int p = 0; p < 8; ++p) {
            float4 v = *(const float4*)&vs[p*128 + k4*4];   // broadcast
            acc[p] = fmaf(v.x, w0, acc[p]);
            acc[p] = fmaf(v.y, w1, acc[p]);
            acc[p] = fmaf(v.z, w2, acc[p]);
            acc[p] = fmaf(v.w, w3, acc[p]);
        }
    }
    #pragma unroll
    for (int p = 0; p < 8; ++p)
        out[(size_t)(opxBase + p)*256 + co] = acc[p] + res_s[p];
}

extern "C" void kernel_launch(void* const* d_in, const int* in_sizes, int n_in,
                              void* d_out, int out_size, void* d_ws, size_t ws_size,
                              hipStream_t stream) {
    const float* x   = (const float*)d_in[0];
    const float* g1  = (const float*)d_in[1];
    const float* be1 = (const float*)d_in[2];
    const float* m1  = (const float*)d_in[3];
    const float* v1  = (const float*)d_in[4];
    const float* W1  = (const float*)d_in[5];
    const float* b1  = (const float*)d_in[6];
    const float* g2  = (const float*)d_in[7];
    const float* be2 = (const float*)d_in[8];
    const float* m2  = (const float*)d_in[9];
    const float* v2  = (const float*)d_in[10];
    const float* W3  = (const float*)d_in[11];
    const float* b3  = (const float*)d_in[12];
    const float* g3  = (const float*)d_in[13];
    const float* be3 = (const float*)d_in[14];
    const float* m3  = (const float*)d_in[15];
    const float* v3  = (const float*)d_in[16];
    const float* W2  = (const float*)d_in[17];
    const float* b2  = (const float*)d_in[18];
    float* out = (float*)d_out;
    float* ws  = (float*)d_ws;

    prep_kernel<<<64, 256, 0, stream>>>(g1, be1, m1, v1, W1, b1, g2, be2, m2,
                                        v2, W3, b3, g3, be3, m3, v3, b2, ws);
    stage1_kernel<<<(NPIX / 64) * 2, 512, 0, stream>>>(x, ws, ws + OFF_U);
    stage2a_kernel<<<448 * 4, 256, 0, stream>>>(ws, ws + OFF_U, ws + OFF_V);
    stage2b_kernel<<<NOPIX / 8, 256, 0, stream>>>(x, W2, ws, ws + OFF_V, out);
}

// Round 9
// 155.314 us; speedup vs baseline: 1.5133x; 1.0046x over previous
//
#include <hip/hip_runtime.h>
#include <hip/hip_bf16.h>

#define EPS 1e-3f
#define NPIX  50176   // 16*56*56
#define NOPIX 12544   // 16*28*28

// ws float offsets
#define OFF_S2   0        // [32][4]  s2
#define OFF_T2   128      // [32][4]  t2
#define OFF_T3   256      // [128]
#define OFF_BSUM 384      // [256]
#define OFF_W3S  640      // [128 k][36 = 9kk x 4ci] pre-scaled by s3
#define OFF_TPH  5248     // [32 g][4 kk][4 lq][8] f16 t' (2048 floats)
#define OFF_WAF  7296     // A-frag table f16: [32 g][4 kk][64 lane][8] (32768 floats)
#define OFF_U    40064    // [32 g][50176 px] ushort4 (bf16, g-planar)

typedef __attribute__((ext_vector_type(4))) float f32x4;
typedef __attribute__((ext_vector_type(8))) _Float16 f16x8;
typedef __attribute__((ext_vector_type(4))) _Float16 f16x4;

__device__ __forceinline__ unsigned short f2bf(float f) {
    unsigned u = __float_as_uint(f);
    return (unsigned short)((u + 0x7fffu + ((u >> 16) & 1u)) >> 16);
}
__device__ __forceinline__ float bf2f(unsigned short s) {
    return __uint_as_float(((unsigned)s) << 16);
}
__device__ __forceinline__ unsigned pk2bf(float lo, float hi) {
    __hip_bfloat162 p = __float22bfloat162_rn(make_float2(lo, hi)); // RNE, lo in bits[15:0]
    union { __hip_bfloat162 h; unsigned u; } c; c.h = p;
    return c.u;
}
__device__ __forceinline__ unsigned short f2h(float f) {
    union { _Float16 h; unsigned short u; } c;
    c.h = (_Float16)f;                 // RNE
    return c.u;
}

__global__ __launch_bounds__(256)
void prep_kernel(const float* __restrict__ g1, const float* __restrict__ be1,
                 const float* __restrict__ m1, const float* __restrict__ v1,
                 const float* __restrict__ W1, const float* __restrict__ b1,
                 const float* __restrict__ g2, const float* __restrict__ be2,
                 const float* __restrict__ m2, const float* __restrict__ v2,
                 const float* __restrict__ W3, const float* __restrict__ b3,
                 const float* __restrict__ g3, const float* __restrict__ be3,
                 const float* __restrict__ m3, const float* __restrict__ v3,
                 const float* __restrict__ b2, float* __restrict__ ws) {
    int gid = blockIdx.x * 256 + threadIdx.x;
    int stride = gridDim.x * 256;
    // t' f16 table: [g][kk][lq][j]  c = kk*32 + lq*8 + j ; t' = be1/s1 - m1
    {
        unsigned short* tph = (unsigned short*)(ws + OFF_TPH);
        for (int i = gid; i < 4096; i += stride) {
            int j  = i & 7, lq = (i >> 3) & 3, kk = (i >> 5) & 3, g = i >> 7;
            int c = kk*32 + lq*8 + j;
            float s = g1[g*128 + c] * rsqrtf(v1[g*128 + c] + EPS);
            tph[i] = f2h(be1[g*128 + c] / s - m1[g*128 + c]);
        }
    }
    // W' A-fragment table (f16): lane l holds A[m=l&15][k=(l>>4)*8+j], m=f (<4)
    {
        unsigned short* wsu = (unsigned short*)(ws + OFF_WAF);
        for (int i = gid; i < 65536; i += stride) {
            int j    = i & 7;
            int lane = (i >> 3) & 63;
            int kk   = (i >> 9) & 3;
            int g    = i >> 11;
            int f    = lane & 15;
            int c    = kk*32 + (lane >> 4)*8 + j;
            unsigned short v = 0;
            if (f < 4) {
                float s = g1[g*128 + c] * rsqrtf(v1[g*128 + c] + EPS);
                v = f2h(s * W1[g*512 + c*4 + f]);
            }
            wsu[i] = v;
        }
    }
    // W3 re-laid [k][kk*4+ci], pre-scaled by s3  (k = g*4+f)
    for (int i = gid; i < 4608; i += stride) {
        int k = i / 36, j = i - k*36;
        int kk = j >> 2, ci = j & 3;
        int g = k >> 2, f = k & 3;
        float s3 = g3[k] * rsqrtf(v3[k] + EPS);
        ws[OFF_W3S + i] = W3[g*144 + kk*16 + ci*4 + f] * s3;
    }
    if (gid < 128) {
        float s2 = g2[gid] * rsqrtf(v2[gid] + EPS);
        ws[OFF_S2 + gid] = s2;
        ws[OFF_T2 + gid] = be2[gid] + (b1[gid] - m2[gid]) * s2;
        float s3 = g3[gid] * rsqrtf(v3[gid] + EPS);
        ws[OFF_T3 + gid] = be3[gid] + (b3[gid] - m3[gid]) * s3;
    } else if (gid >= 256 && gid < 512) {
        int co = gid - 256;
        float acc = 0.f;
        for (int g = 0; g < 32; ++g) acc += b2[g*256 + co];
        ws[OFF_BSUM + co] = acc;
    }
}

// Stage 1 (fp16 MFMA): grid = 784 tiles x 2 g-halves; block 512 = 8 waves;
// wave = 2 groups x 64 px. x converted f32->f16 at staging (once); z-compute
// is pure v_pk_add_f16/v_pk_max_f16 (2 elem/inst), no cvt in the g-loop.
__global__ __launch_bounds__(512, 4)
void stage1_kernel(const float* __restrict__ x,
                   const float* __restrict__ tabs,   // ws
                   float* __restrict__ uout) {       // ws + OFF_U
    __shared__ uint4 xs[1024];     // 16 KB: [64 px][16 chunk ^ (px&15)], chunk = 8 f16
    int tid = threadIdx.x;
    int tile  = blockIdx.x >> 1;
    int ghalf = blockIdx.x & 1;

    // stage x -> f16 LDS (coalesced reads; paired ds_write_b64, 2-way free)
    {
        const float4* xg = (const float4*)x + (size_t)tile * 2048;
        #pragma unroll
        for (int r = 0; r < 4; ++r) {
            int i = tid + 512*r;
            int px = i >> 5, c4 = i & 31;
            float4 v = xg[i];
            union { f16x4 h; uint2 u; } hv;
            hv.h = (f16x4){(_Float16)v.x, (_Float16)v.y, (_Float16)v.z, (_Float16)v.w};
            int cc = c4 >> 1, hf = c4 & 1;
            ((uint2*)xs)[(px*16 + (cc ^ (px & 15)))*2 + hf] = hv.u;
        }
    }

    int lane = tid & 63;
    int wid  = tid >> 6;                                   // 0..7
    int g0   = __builtin_amdgcn_readfirstlane(ghalf*16 + wid*2);
    int l15  = lane & 15;
    int lq   = lane >> 4;                                  // k-chunk: c = kk*32 + lq*8 + j

    union U4H { uint4 u; f16x8 h; };
    // A-fragments: 2 g x 4 kk = 32 VGPR (f16)
    U4H af[2][4];
    {
        const uint4* wafp = (const uint4*)(tabs + OFF_WAF);
        #pragma unroll
        for (int gi = 0; gi < 2; ++gi)
            #pragma unroll
            for (int kk = 0; kk < 4; ++kk)
                af[gi][kk].u = wafp[((g0 + gi)*4 + kk)*64 + lane];
    }
    // t' f16 in registers: 2 g x 4 kk x 16B = 32 VGPR
    U4H tph[2][4];
    {
        const uint4* tphp = (const uint4*)(tabs + OFF_TPH);
        #pragma unroll
        for (int gi = 0; gi < 2; ++gi)
            #pragma unroll
            for (int kk = 0; kk < 4; ++kk)
                tph[gi][kk].u = tphp[((g0 + gi)*4 + kk)*4 + lq];
    }
    __syncthreads();

    uint2* Uo = (uint2*)uout;
    const f32x4 zro = {0.f, 0.f, 0.f, 0.f};
    const f16x8 zh = {0, 0, 0, 0, 0, 0, 0, 0};

    #pragma unroll 1
    for (int t = 0; t < 4; ++t) {
        int pxl = t*16 + l15;
        U4H xf[4];
        #pragma unroll
        for (int kk = 0; kk < 4; ++kk)
            xf[kk].u = xs[pxl*16 + ((kk*4 + lq) ^ (pxl & 15))];
        #pragma unroll
        for (int gi = 0; gi < 2; ++gi) {
            int g = g0 + gi;
            f32x4 acc = zro;
            #pragma unroll
            for (int kk = 0; kk < 4; ++kk) {
                f16x8 z = __builtin_elementwise_max(xf[kk].h + tph[gi][kk].h, zh);
                acc = __builtin_amdgcn_mfma_f32_16x16x32_f16(af[gi][kk].h, z, acc, 0, 0, 0);
            }
            const float4 s2v = ((const float4*)(tabs + OFF_S2))[g];
            const float4 t2v = ((const float4*)(tabs + OFF_T2))[g];
            float o0 = fmaxf(fmaf(acc[0], s2v.x, t2v.x), 0.f);
            float o1 = fmaxf(fmaf(acc[1], s2v.y, t2v.y), 0.f);
            float o2 = fmaxf(fmaf(acc[2], s2v.z, t2v.z), 0.f);
            float o3 = fmaxf(fmaf(acc[3], s2v.w, t2v.w), 0.f);
            uint2 val;
            val.x = pk2bf(o0, o1);
            val.y = pk2bf(o2, o3);
            if (lane < 16)
                Uo[(size_t)g * NPIX + tile*64 + t*16 + lane] = val;
        }
    }
}

// Stage 2 (fused conv3x3 + GEMM + residual): block = half-row (14 opx),
// 256 thr, grid 896. U patch (3x30x32 ushort4, 23 KB) staged once; conv
// writes vs[14][128] to LDS (V never hits global); phase B = stage2b's
// proven broadcast-GEMM. ~30.5 KB LDS -> 5 blocks/CU.
__global__ __launch_bounds__(256)
void stage2_kernel(const float* __restrict__ x,
                   const float* __restrict__ W2,     // [128,256]
                   const float* __restrict__ tabs,   // ws
                   const float* __restrict__ U,      // ws + OFF_U (bf16)
                   float* __restrict__ out) {
    __shared__ ushort4 patch[3*30*32];   // [r][c][g ^ c]   23040 B
    __shared__ float vs[14*128];         // [opx_l][k]       7168 B
    __shared__ float res_s[14];

    int tid = threadIdx.x;
    int row = blockIdx.x >> 1;           // b*28 + oh
    int qh  = blockIdx.x & 1;            // half: opx_l base = qh*14
    int b = row / 28, oh = row - b*28;

    // ---- stage U patch: rows ih = 2oh-1..2oh+1, cols ic = 28qh-1 .. 28qh+28 ----
    {
        const ushort4* Uu = (const ushort4*)U;
        #pragma unroll 1
        for (int i = tid; i < 2880; i += 256) {
            int g = i / 90;
            int rem = i - g*90;
            int r = rem / 30;            // 0..2
            int c = rem - r*30;          // 0..29
            int ih = 2*oh - 1 + r;
            int ic = 28*qh - 1 + c;
            ushort4 v = make_ushort4(0, 0, 0, 0);
            if (ih >= 0 && ic >= 0 && ic < 56)
                v = Uu[(size_t)g * NPIX + (b*56 + ih)*56 + ic];
            patch[(r*30 + c)*32 + (g ^ c)] = v;
        }
    }

    // ---- residual: res[p] = sum_c x[b, 2oh, 2(qh*14+p), c] ----
    {
        int p = tid >> 4, l = tid & 15;
        if (p < 14) {
            int ow = qh*14 + p;
            const float* xp = x + (size_t)((b*56 + 2*oh)*56 + 2*ow) * 128 + l;
            float rv = 0.f;
            #pragma unroll
            for (int c = 0; c < 8; ++c) rv += xp[c*16];
            #pragma unroll
            for (int off = 8; off; off >>= 1) rv += __shfl_down(rv, off, 16);
            if (l == 0) res_s[p] = rv;
        }
    }

    // weights into VGPRs: 9 float4 per thread (L2-hot table)
    int k = tid & 127, s = tid >> 7;     // s in {0,1}
    int g = k >> 2;
    float4 w[9];
    {
        const float4* wk = (const float4*)(tabs + OFF_W3S + k*36);
        #pragma unroll
        for (int kk = 0; kk < 9; ++kk) w[kk] = wk[kk];
    }
    float t3 = tabs[OFF_T3 + k];
    __syncthreads();

    // ---- conv: opx_l = s + 2j (parity split), each ushort4 read broadcast x4 f ----
    #pragma unroll 1
    for (int j = 0; j < 7; ++j) {
        int opx_l = s + 2*j;
        float acc = 0.f;
        #pragma unroll
        for (int kh = 0; kh < 3; ++kh) {
            #pragma unroll
            for (int kw = 0; kw < 3; ++kw) {
                int cc = 2*opx_l + kw;   // 0..28
                ushort4 u = patch[(kh*30 + cc)*32 + (g ^ cc)];
                float4 wv = w[kh*3 + kw];
                acc = fmaf(bf2f(u.x), wv.x, acc);
                acc = fmaf(bf2f(u.y), wv.y, acc);
                acc = fmaf(bf2f(u.z), wv.z, acc);
                acc = fmaf(bf2f(u.w), wv.w, acc);
            }
        }
        vs[opx_l*128 + k] = fmaxf(acc + t3, 0.f);
    }
    __syncthreads();

    // ---- phase B: out[opx][co] = vs @ W2 + bsum + res, thread = co ----
    int co = tid;
    float acc[14];
    {
        float bs = tabs[OFF_BSUM + co];
        #pragma unroll
        for (int p = 0; p < 14; ++p) acc[p] = bs;
    }
    const float* W2c = W2 + co;
    #pragma unroll 4
    for (int k4 = 0; k4 < 32; ++k4) {
        float w0 = W2c[(4*k4+0)*256];
        float w1 = W2c[(4*k4+1)*256];
        float w2 = W2c[(4*k4+2)*256];
        float w3 = W2c[(4*k4+3)*256];
        #pragma unroll
        for (int p = 0; p < 14; ++p) {
            float4 v = *(const float4*)&vs[p*128 + k4*4];   // broadcast
            acc[p] = fmaf(v.x, w0, acc[p]);
            acc[p] = fmaf(v.y, w1, acc[p]);
            acc[p] = fmaf(v.z, w2, acc[p]);
            acc[p] = fmaf(v.w, w3, acc[p]);
        }
    }
    size_t obase = ((size_t)row * 28 + qh*14) * 256;
    #pragma unroll
    for (int p = 0; p < 14; ++p)
        out[obase + (size_t)p*256 + co] = acc[p] + res_s[p];
}

extern "C" void kernel_launch(void* const* d_in, const int* in_sizes, int n_in,
                              void* d_out, int out_size, void* d_ws, size_t ws_size,
                              hipStream_t stream) {
    const float* x   = (const float*)d_in[0];
    const float* g1  = (const float*)d_in[1];
    const float* be1 = (const float*)d_in[2];
    const float* m1  = (const float*)d_in[3];
    const float* v1  = (const float*)d_in[4];
    const float* W1  = (const float*)d_in[5];
    const float* b1  = (const float*)d_in[6];
    const float* g2  = (const float*)d_in[7];
    const float* be2 = (const float*)d_in[8];
    const float* m2  = (const float*)d_in[9];
    const float* v2  = (const float*)d_in[10];
    const float* W3  = (const float*)d_in[11];
    const float* b3  = (const float*)d_in[12];
    const float* g3  = (const float*)d_in[13];
    const float* be3 = (const float*)d_in[14];
    const float* m3  = (const float*)d_in[15];
    const float* v3  = (const float*)d_in[16];
    const float* W2  = (const float*)d_in[17];
    const float* b2  = (const float*)d_in[18];
    float* out = (float*)d_out;
    float* ws  = (float*)d_ws;

    prep_kernel<<<64, 256, 0, stream>>>(g1, be1, m1, v1, W1, b1, g2, be2, m2,
                                        v2, W3, b3, g3, be3, m3, v3, b2, ws);
    stage1_kernel<<<(NPIX / 64) * 2, 512, 0, stream>>>(x, ws, ws + OFF_U);
    stage2_kernel<<<448 * 2, 256, 0, stream>>>(x, W2, ws, ws + OFF_U, out);
}

// Round 10
// 136.989 us; speedup vs baseline: 1.7158x; 1.1338x over previous
//
#include <hip/hip_runtime.h>
#include <hip/hip_bf16.h>

#define EPS 1e-3f
#define NPIX  50176   // 16*56*56
#define NOPIX 12544   // 16*28*28

// ws float offsets
#define OFF_S2   0        // [32][4]  s2
#define OFF_T2   128      // [32][4]  t2
#define OFF_T3   256      // [128]
#define OFF_BSUM 384      // [256]
#define OFF_W3H  640      // f16 [128 k][9 tap][4 ci] pre-scaled by s3 (4608 f16 = 2304 fl)
#define OFF_TPH  2944     // f16 [32 g][4 kk][4 lq][8] t' (4096 f16 = 2048 fl)
#define OFF_WAF  4992     // A-frag f16 W1: [32 g][4 kk][64 lane][8] (32768 f16 = 16384 fl)
#define OFF_WB2  21376    // A-frag f16 W2: [16 ct][4 kk][64 lane][8] (32768 f16 = 16384 fl)
#define OFF_U    37760    // [32 g][50176 px] f16x4 (8B), g-planar

typedef __attribute__((ext_vector_type(4))) float f32x4;
typedef __attribute__((ext_vector_type(8))) _Float16 f16x8;
typedef __attribute__((ext_vector_type(4))) _Float16 f16x4;
typedef __attribute__((ext_vector_type(2))) _Float16 f16x2;

__device__ __forceinline__ unsigned short f2h(float f) {
    union { _Float16 h; unsigned short u; } c;
    c.h = (_Float16)f;                 // RNE
    return c.u;
}

__global__ __launch_bounds__(256)
void prep_kernel(const float* __restrict__ g1, const float* __restrict__ be1,
                 const float* __restrict__ m1, const float* __restrict__ v1,
                 const float* __restrict__ W1, const float* __restrict__ b1,
                 const float* __restrict__ g2, const float* __restrict__ be2,
                 const float* __restrict__ m2, const float* __restrict__ v2,
                 const float* __restrict__ W3, const float* __restrict__ b3,
                 const float* __restrict__ g3, const float* __restrict__ be3,
                 const float* __restrict__ m3, const float* __restrict__ v3,
                 const float* __restrict__ W2, const float* __restrict__ b2,
                 float* __restrict__ ws) {
    int gid = blockIdx.x * 256 + threadIdx.x;
    int stride = gridDim.x * 256;
    // t' f16 table: [g][kk][lq][j]  c = kk*32 + lq*8 + j ; t' = be1/s1 - m1
    {
        unsigned short* tph = (unsigned short*)(ws + OFF_TPH);
        for (int i = gid; i < 4096; i += stride) {
            int j  = i & 7, lq = (i >> 3) & 3, kk = (i >> 5) & 3, g = i >> 7;
            int c = kk*32 + lq*8 + j;
            float s = g1[g*128 + c] * rsqrtf(v1[g*128 + c] + EPS);
            tph[i] = f2h(be1[g*128 + c] / s - m1[g*128 + c]);
        }
    }
    // W1' A-frag table (f16): lane l holds A[m=l&15][k=(l>>4)*8+j], m=f (<4)
    {
        unsigned short* wsu = (unsigned short*)(ws + OFF_WAF);
        for (int i = gid; i < 32768; i += stride) {
            int j    = i & 7;
            int lane = (i >> 3) & 63;
            int kk   = (i >> 9) & 3;
            int g    = i >> 11;
            int f    = lane & 15;
            int c    = kk*32 + (lane >> 4)*8 + j;
            unsigned short v = 0;
            if (f < 4) {
                float s = g1[g*128 + c] * rsqrtf(v1[g*128 + c] + EPS);
                v = f2h(s * W1[g*512 + c*4 + f]);
            }
            wsu[i] = v;
        }
    }
    // W2 A-frag table (f16): [ct][kk][lane][j]; m=co=ct*16+(l&15), k=c=kk*32+(l>>4)*8+j
    {
        unsigned short* wb = (unsigned short*)(ws + OFF_WB2);
        for (int i = gid; i < 32768; i += stride) {
            int j    = i & 7;
            int lane = (i >> 3) & 63;
            int kk   = (i >> 9) & 3;
            int ct   = i >> 11;          // 0..15
            int co = ct*16 + (lane & 15);
            int c  = kk*32 + (lane >> 4)*8 + j;
            wb[i] = f2h(W2[c*256 + co]);
        }
    }
    // W3 f16 [k][tap][ci], pre-scaled by s3  (k = g*4+f)
    {
        unsigned short* w3h = (unsigned short*)(ws + OFF_W3H);
        for (int i = gid; i < 4608; i += stride) {
            int k = i / 36, j = i - k*36;
            int tap = j >> 2, ci = j & 3;
            int g = k >> 2, f = k & 3;
            float s3 = g3[k] * rsqrtf(v3[k] + EPS);
            w3h[i] = f2h(W3[g*144 + tap*16 + ci*4 + f] * s3);
        }
    }
    if (gid < 128) {
        float s2 = g2[gid] * rsqrtf(v2[gid] + EPS);
        ws[OFF_S2 + gid] = s2;
        ws[OFF_T2 + gid] = be2[gid] + (b1[gid] - m2[gid]) * s2;
        float s3 = g3[gid] * rsqrtf(v3[gid] + EPS);
        ws[OFF_T3 + gid] = be3[gid] + (b3[gid] - m3[gid]) * s3;
    } else if (gid >= 256 && gid < 512) {
        int co = gid - 256;
        float acc = 0.f;
        for (int g = 0; g < 32; ++g) acc += b2[g*256 + co];
        ws[OFF_BSUM + co] = acc;
    }
}

// Stage 1 (fp16 MFMA): grid = 784 tiles x 2 g-halves; block 512 = 8 waves;
// wave = 2 groups x 64 px. U output now f16 (consumed by f16 conv + MFMA GEMM).
__global__ __launch_bounds__(512, 4)
void stage1_kernel(const float* __restrict__ x,
                   const float* __restrict__ tabs,   // ws
                   float* __restrict__ uout) {       // ws + OFF_U
    __shared__ uint4 xs[1024];     // 16 KB: [64 px][16 chunk ^ (px&15)], chunk = 8 f16
    int tid = threadIdx.x;
    int tile  = blockIdx.x >> 1;
    int ghalf = blockIdx.x & 1;

    {
        const float4* xg = (const float4*)x + (size_t)tile * 2048;
        #pragma unroll
        for (int r = 0; r < 4; ++r) {
            int i = tid + 512*r;
            int px = i >> 5, c4 = i & 31;
            float4 v = xg[i];
            union { f16x4 h; uint2 u; } hv;
            hv.h = (f16x4){(_Float16)v.x, (_Float16)v.y, (_Float16)v.z, (_Float16)v.w};
            int cc = c4 >> 1, hf = c4 & 1;
            ((uint2*)xs)[(px*16 + (cc ^ (px & 15)))*2 + hf] = hv.u;
        }
    }

    int lane = tid & 63;
    int wid  = tid >> 6;
    int g0   = __builtin_amdgcn_readfirstlane(ghalf*16 + wid*2);
    int l15  = lane & 15;
    int lq   = lane >> 4;

    union U4H { uint4 u; f16x8 h; };
    U4H af[2][4];
    {
        const uint4* wafp = (const uint4*)(tabs + OFF_WAF);
        #pragma unroll
        for (int gi = 0; gi < 2; ++gi)
            #pragma unroll
            for (int kk = 0; kk < 4; ++kk)
                af[gi][kk].u = wafp[((g0 + gi)*4 + kk)*64 + lane];
    }
    U4H tph[2][4];
    {
        const uint4* tphp = (const uint4*)(tabs + OFF_TPH);
        #pragma unroll
        for (int gi = 0; gi < 2; ++gi)
            #pragma unroll
            for (int kk = 0; kk < 4; ++kk)
                tph[gi][kk].u = tphp[((g0 + gi)*4 + kk)*4 + lq];
    }
    __syncthreads();

    uint2* Uo = (uint2*)uout;
    const f32x4 zro = {0.f, 0.f, 0.f, 0.f};
    const f16x8 zh = {0, 0, 0, 0, 0, 0, 0, 0};

    #pragma unroll 1
    for (int t = 0; t < 4; ++t) {
        int pxl = t*16 + l15;
        U4H xf[4];
        #pragma unroll
        for (int kk = 0; kk < 4; ++kk)
            xf[kk].u = xs[pxl*16 + ((kk*4 + lq) ^ (pxl & 15))];
        #pragma unroll
        for (int gi = 0; gi < 2; ++gi) {
            int g = g0 + gi;
            f32x4 acc = zro;
            #pragma unroll
            for (int kk = 0; kk < 4; ++kk) {
                f16x8 z = __builtin_elementwise_max(xf[kk].h + tph[gi][kk].h, zh);
                acc = __builtin_amdgcn_mfma_f32_16x16x32_f16(af[gi][kk].h, z, acc, 0, 0, 0);
            }
            const float4 s2v = ((const float4*)(tabs + OFF_S2))[g];
            const float4 t2v = ((const float4*)(tabs + OFF_T2))[g];
            float o0 = fmaxf(fmaf(acc[0], s2v.x, t2v.x), 0.f);
            float o1 = fmaxf(fmaf(acc[1], s2v.y, t2v.y), 0.f);
            float o2 = fmaxf(fmaf(acc[2], s2v.z, t2v.z), 0.f);
            float o3 = fmaxf(fmaf(acc[3], s2v.w, t2v.w), 0.f);
            union { f16x4 h; uint2 u; } val;
            val.h = (f16x4){(_Float16)o0, (_Float16)o1, (_Float16)o2, (_Float16)o3};
            if (lane < 16)
                Uo[(size_t)g * NPIX + tile*64 + t*16 + lane] = val.u;
        }
    }
}

// Stage 2 (fused, f16 conv + MFMA GEMM): block = half-row (14 opx), 256 thr,
// grid 896. Conv: per tap 1 ds_read_b64 + 2 v_pk_fma_f16 (split accumulators).
// V -> 4KB swizzled f16 LDS; phase B: D[co16][px16] MFMA tiles, A = W2-f16
// table (L2-hot), B = V frags (conflict-free b128). ~27 KB LDS -> 5 blk/CU.
__global__ __launch_bounds__(256)
void stage2_kernel(const float* __restrict__ x,
                   const float* __restrict__ tabs,   // ws
                   const float* __restrict__ U,      // ws + OFF_U (f16)
                   float* __restrict__ out) {
    __shared__ ushort4 patch[3*30*32];   // [r][c][g ^ c]   23040 B
    __shared__ uint4 vsb[256];           // [16 px][16 chunk ^ px] of 8 f16  4096 B
    __shared__ float res_s[16];

    int tid = threadIdx.x;
    int row = blockIdx.x >> 1;           // b*28 + oh
    int qh  = blockIdx.x & 1;            // half: opx base = qh*14
    int b = row / 28, oh = row - b*28;

    // ---- stage U patch: rows ih = 2oh-1..2oh+1, cols ic = 28qh-1 .. 28qh+28 ----
    {
        const ushort4* Uu = (const ushort4*)U;
        #pragma unroll 1
        for (int i = tid; i < 2880; i += 256) {
            int g = i / 90;
            int rem = i - g*90;
            int r = rem / 30;            // 0..2
            int c = rem - r*30;          // 0..29
            int ih = 2*oh - 1 + r;
            int ic = 28*qh - 1 + c;
            ushort4 v = make_ushort4(0, 0, 0, 0);
            if (ih >= 0 && ic >= 0 && ic < 56)
                v = Uu[(size_t)g * NPIX + (b*56 + ih)*56 + ic];
            patch[(r*30 + c)*32 + (g ^ c)] = v;
        }
    }

    // ---- residual: res[p] = sum_c x[b, 2oh, 2(qh*14+p), c] ----
    {
        int p = tid >> 4, l = tid & 15;
        if (p < 14) {
            int ow = qh*14 + p;
            const float* xp = x + (size_t)((b*56 + 2*oh)*56 + 2*ow) * 128 + l;
            float rv = 0.f;
            #pragma unroll
            for (int c = 0; c < 8; ++c) rv += xp[c*16];
            #pragma unroll
            for (int off = 8; off; off >>= 1) rv += __shfl_down(rv, off, 16);
            if (l == 0) res_s[p] = rv;
        }
    }

    // conv weights: 9 x f16x4 (uint2) per thread, L2-hot
    int k = tid & 127, s = tid >> 7;     // s in {0,1}
    int g = k >> 2;
    uint2 wk[9];
    {
        const uint2* wk2 = (const uint2*)((const unsigned short*)(tabs + OFF_W3H) + (size_t)k*36);
        #pragma unroll
        for (int tap = 0; tap < 9; ++tap) wk[tap] = wk2[tap];
    }
    float t3 = tabs[OFF_T3 + k];
    __syncthreads();

    // ---- conv (f16 packed): opx = s + 2j; per tap: ds_read_b64 + 2 pk_fma ----
    #pragma unroll 1
    for (int j = 0; j < 7; ++j) {
        int opx_l = s + 2*j;
        f16x2 acc0 = {0, 0}, acc1 = {0, 0};
        #pragma unroll
        for (int kh = 0; kh < 3; ++kh) {
            #pragma unroll
            for (int kw = 0; kw < 3; ++kw) {
                int cc = 2*opx_l + kw;   // 0..28
                union { ushort4 su; f16x4 h; } u;
                u.su = patch[(kh*30 + cc)*32 + (g ^ cc)];
                union { uint2 u2; f16x4 h; } wv;
                wv.u2 = wk[kh*3 + kw];
                f16x2 ulo = __builtin_shufflevector(u.h, u.h, 0, 1);
                f16x2 uhi = __builtin_shufflevector(u.h, u.h, 2, 3);
                f16x2 wlo = __builtin_shufflevector(wv.h, wv.h, 0, 1);
                f16x2 whi = __builtin_shufflevector(wv.h, wv.h, 2, 3);
                acc0 = acc0 + ulo * wlo;   // v_pk_fma_f16 (ffp-contract)
                acc1 = acc1 + uhi * whi;
            }
        }
        float a = ((float)acc0[0] + (float)acc0[1]) + ((float)acc1[0] + (float)acc1[1]);
        float v = fmaxf(a + t3, 0.f);
        ((unsigned short*)vsb)[(opx_l*16 + ((k >> 3) ^ opx_l))*8 + (k & 7)] = f2h(v);
    }
    __syncthreads();

    // ---- phase B: out[px][co] = V @ W2 via MFMA; D[m=co16][n=px16] ----
    {
        int lane = tid & 63;
        int wid  = tid >> 6;             // 0..3, owns co-tiles wid*4..wid*4+3
        int l15  = lane & 15;            // px
        int lq   = lane >> 4;
        union U4H { uint4 u; f16x8 h; };
        U4H bf[4];
        #pragma unroll
        for (int kk = 0; kk < 4; ++kk)
            bf[kk].u = vsb[l15*16 + ((kk*4 + lq) ^ l15)];
        const uint4* wb2p = (const uint4*)(tabs + OFF_WB2);
        size_t obase = ((size_t)row * 28 + qh*14) * 256;
        float rv = res_s[l15];
        #pragma unroll
        for (int c4 = 0; c4 < 4; ++c4) {
            int ct = wid*4 + c4;
            U4H af2[4];
            #pragma unroll
            for (int kk = 0; kk < 4; ++kk)
                af2[kk].u = wb2p[(ct*4 + kk)*64 + lane];
            f32x4 acc = {0.f, 0.f, 0.f, 0.f};
            #pragma unroll
            for (int kk = 0; kk < 4; ++kk)
                acc = __builtin_amdgcn_mfma_f32_16x16x32_f16(af2[kk].h, bf[kk].h, acc, 0, 0, 0);
            float4 bs = *(const float4*)(tabs + OFF_BSUM + ct*16 + lq*4);
            if (l15 < 14) {
                float4 o;
                o.x = acc[0] + bs.x + rv;
                o.y = acc[1] + bs.y + rv;
                o.z = acc[2] + bs.z + rv;
                o.w = acc[3] + bs.w + rv;
                *(float4*)&out[obase + (size_t)l15*256 + ct*16 + lq*4] = o;
            }
        }
    }
}

extern "C" void kernel_launch(void* const* d_in, const int* in_sizes, int n_in,
                              void* d_out, int out_size, void* d_ws, size_t ws_size,
                              hipStream_t stream) {
    const float* x   = (const float*)d_in[0];
    const float* g1  = (const float*)d_in[1];
    const float* be1 = (const float*)d_in[2];
    const float* m1  = (const float*)d_in[3];
    const float* v1  = (const float*)d_in[4];
    const float* W1  = (const float*)d_in[5];
    const float* b1  = (const float*)d_in[6];
    const float* g2  = (const float*)d_in[7];
    const float* be2 = (const float*)d_in[8];
    const float* m2  = (const float*)d_in[9];
    const float* v2  = (const float*)d_in[10];
    const float* W3  = (const float*)d_in[11];
    const float* b3  = (const float*)d_in[12];
    const float* g3  = (const float*)d_in[13];
    const float* be3 = (const float*)d_in[14];
    const float* m3  = (const float*)d_in[15];
    const float* v3  = (const float*)d_in[16];
    const float* W2  = (const float*)d_in[17];
    const float* b2  = (const float*)d_in[18];
    float* out = (float*)d_out;
    float* ws  = (float*)d_ws;

    prep_kernel<<<64, 256, 0, stream>>>(g1, be1, m1, v1, W1, b1, g2, be2, m2,
                                        v2, W3, b3, g3, be3, m3, v3, W2, b2, ws);
    stage1_kernel<<<(NPIX / 64) * 2, 512, 0, stream>>>(x, ws, ws + OFF_U);
    stage2_kernel<<<448 * 2, 256, 0, stream>>>(x, ws, ws + OFF_U, out);
}